// Round 1
// baseline (395.119 us; speedup 1.0000x reference)
//
#include <hip/hip_runtime.h>

// MutiHeadSelfAttention: B=4,S=2048,D=1024,H=16,E=64
// Pipeline: cvt_x -> cvt_w (transpose) -> fused QKVR GEMM (bf16 MFMA) -> flash attn (+= into out)

typedef __bf16 bf16x8 __attribute__((ext_vector_type(8)));
typedef float  f32x4  __attribute__((ext_vector_type(4)));
typedef short  short8 __attribute__((ext_vector_type(8)));
typedef short  short4v __attribute__((ext_vector_type(4)));
typedef float  float4v __attribute__((ext_vector_type(4)));

#define LOG2E 1.44269504088896f

__device__ __forceinline__ unsigned short f2bf(float f) {
  unsigned u = __builtin_bit_cast(unsigned, f);
  u += 0x7fffu + ((u >> 16) & 1u);   // RNE
  return (unsigned short)(u >> 16);
}

#if defined(__has_builtin)
#if __has_builtin(__builtin_amdgcn_global_load_lds)
#define USE_GLL 1
#endif
#endif
#ifndef USE_GLL
#define USE_GLL 0
#endif

// ---------------- x fp32 -> bf16 ----------------
__global__ __launch_bounds__(256) void k_cvt_x(const float* __restrict__ x,
                                               short* __restrict__ Xb) {
  const size_t i = ((size_t)blockIdx.x * 256 + threadIdx.x) * 4;
  float4v f = *(const float4v*)(x + i);
  short4v o;
  o[0] = (short)f2bf(f[0]); o[1] = (short)f2bf(f[1]);
  o[2] = (short)f2bf(f[2]); o[3] = (short)f2bf(f[3]);
  *(short4v*)(Xb + i) = o;
}

// ---------------- W [1024k][1024n] fp32 x4 -> Wc[4096 n][1024 k] bf16 (B^T) ----------------
__global__ __launch_bounds__(256) void k_cvt_w(const float* __restrict__ Wq,
                                               const float* __restrict__ Wk,
                                               const float* __restrict__ Wv,
                                               const float* __restrict__ Wr,
                                               short* __restrict__ Wc) {
  const int bid = blockIdx.x;
  const int w = bid >> 8;           // which weight
  const int t = bid & 255;
  const int tr = t >> 4, tc = t & 15;  // 64x64 tile coords (k-tile, n-tile)
  const float* Ws = (w == 0) ? Wq : (w == 1) ? Wk : (w == 2) ? Wv : Wr;
  __shared__ float T[64][65];
  const int tx = threadIdx.x & 63, ty = threadIdx.x >> 6;
#pragma unroll
  for (int i = 0; i < 16; ++i)
    T[i * 4 + ty][tx] = Ws[(size_t)(tr * 64 + i * 4 + ty) * 1024 + tc * 64 + tx];
  __syncthreads();
#pragma unroll
  for (int i = 0; i < 16; ++i) {
    const int n = tc * 64 + i * 4 + ty;
    Wc[((size_t)w * 1024 + n) * 1024 + tr * 64 + tx] = (short)f2bf(T[tx][i * 4 + ty]);
  }
}

// ---------------- fused QKVR GEMM: C[8192][4096] = Xb @ Wc^T ----------------
// epilogue: n<3072 -> relu, bf16 store into Q/K/V [B][H][S][E]; n>=3072 -> fp32 residual into Out
__global__ __launch_bounds__(256) void k_gemm(const short* __restrict__ Xb,
                                              const short* __restrict__ Wc,
                                              const float* __restrict__ bq,
                                              const float* __restrict__ bk2,
                                              const float* __restrict__ bv,
                                              const float* __restrict__ br,
                                              short* __restrict__ Qb,
                                              short* __restrict__ Kb,
                                              short* __restrict__ Vb,
                                              float* __restrict__ Out) {
  __shared__ short As[128 * 32];
  __shared__ short Bs[128 * 32];
  const int tid = threadIdx.x, wid = tid >> 6, lane = tid & 63;
  const int lr = lane & 15, hi = lane >> 4;
  const int bm = blockIdx.x & 63, bn = blockIdx.x >> 6;  // 64 M-tiles x 32 N-tiles
  const int m0 = bm * 128, n0 = bn * 128;
  const int wr = wid >> 1, wc = wid & 1;

  f32x4 acc[4][4] = {};

  const int c0 = wid * 2;                // this wave stages chunks c0, c0+1 of each tile
  const int srow = lane >> 2;            // row within 16-row chunk
  const int scol = (lane & 3) * 8;       // bf16 col offset

  for (int k0 = 0; k0 < 1024; k0 += 32) {
    __syncthreads();
    const short* a0 = Xb + (size_t)(m0 + c0 * 16 + srow) * 1024 + k0 + scol;
    const short* a1 = Xb + (size_t)(m0 + (c0 + 1) * 16 + srow) * 1024 + k0 + scol;
    const short* b0 = Wc + (size_t)(n0 + c0 * 16 + srow) * 1024 + k0 + scol;
    const short* b1 = Wc + (size_t)(n0 + (c0 + 1) * 16 + srow) * 1024 + k0 + scol;
#if USE_GLL
    __builtin_amdgcn_global_load_lds((const __attribute__((address_space(1))) void*)a0,
                                     (__attribute__((address_space(3))) void*)&As[c0 * 512], 16, 0, 0);
    __builtin_amdgcn_global_load_lds((const __attribute__((address_space(1))) void*)a1,
                                     (__attribute__((address_space(3))) void*)&As[(c0 + 1) * 512], 16, 0, 0);
    __builtin_amdgcn_global_load_lds((const __attribute__((address_space(1))) void*)b0,
                                     (__attribute__((address_space(3))) void*)&Bs[c0 * 512], 16, 0, 0);
    __builtin_amdgcn_global_load_lds((const __attribute__((address_space(1))) void*)b1,
                                     (__attribute__((address_space(3))) void*)&Bs[(c0 + 1) * 512], 16, 0, 0);
#else
    *(short8*)&As[c0 * 512 + lane * 8] = *(const short8*)a0;
    *(short8*)&As[(c0 + 1) * 512 + lane * 8] = *(const short8*)a1;
    *(short8*)&Bs[c0 * 512 + lane * 8] = *(const short8*)b0;
    *(short8*)&Bs[(c0 + 1) * 512 + lane * 8] = *(const short8*)b1;
#endif
    __syncthreads();

    bf16x8 af[4], bfr[4];
#pragma unroll
    for (int i = 0; i < 4; ++i)
      af[i] = *(const bf16x8*)&As[(wr * 64 + i * 16 + lr) * 32 + hi * 8];
#pragma unroll
    for (int j = 0; j < 4; ++j)
      bfr[j] = *(const bf16x8*)&Bs[(wc * 64 + j * 16 + lr) * 32 + hi * 8];
#pragma unroll
    for (int i = 0; i < 4; ++i)
#pragma unroll
      for (int j = 0; j < 4; ++j)
        acc[i][j] = __builtin_amdgcn_mfma_f32_16x16x32_bf16(af[i], bfr[j], acc[i][j], 0, 0, 0);
  }

  // epilogue
#pragma unroll
  for (int i = 0; i < 4; ++i) {
    const int mbase = m0 + wr * 64 + i * 16 + hi * 4;
#pragma unroll
    for (int j = 0; j < 4; ++j) {
      const int n = n0 + wc * 64 + j * 16 + lr;
      const float* bp = (n < 2048) ? (n < 1024 ? bq : bk2) : (n < 3072 ? bv : br);
      const float bias = bp[n & 1023];
#pragma unroll
      for (int r = 0; r < 4; ++r) {
        float v = acc[i][j][r] + bias;
        const int m = mbase + r;
        if (n < 3072) {
          v = fmaxf(v, 0.0f);
          const int which = n >> 10;
          const int nn = n & 1023, h = nn >> 6, e = nn & 63;
          short* dst = (which == 0) ? Qb : (which == 1) ? Kb : Vb;
          const int bb = m >> 11, ss = m & 2047;
          dst[(((size_t)bb * 16 + h) * 2048 + ss) * 64 + e] = (short)f2bf(v);
        } else {
          Out[(size_t)m * 1024 + (n - 3072)] = v;
        }
      }
    }
  }
}

// ---------------- flash attention, += into Out ----------------
// grid: 64 (b,h) x 32 q-tiles of 64. Block: 4 waves x 16 q-rows.
__global__ __launch_bounds__(256) void k_attn(const short* __restrict__ Qb,
                                              const short* __restrict__ Kb,
                                              const short* __restrict__ Vb,
                                              float* __restrict__ Out) {
  __shared__ short K_lds[64 * 72];
  __shared__ short V_lds[64 * 72];
  __shared__ short P_lds[4][16 * 72];

  const int tid = threadIdx.x, wid = tid >> 6, lane = tid & 63;
  const int lr = lane & 15, hi = lane >> 4;
  const int bh = blockIdx.x >> 5;        // b*16+h
  const int q0 = (blockIdx.x & 31) * 64;
  const size_t hbase = (size_t)bh * 2048 * 64;

  // Q fragments held in registers: rows q0+wid*16+lr, e halves
  bf16x8 aq[2];
  {
    const short* qp = Qb + hbase + (size_t)(q0 + wid * 16 + lr) * 64 + hi * 8;
    aq[0] = *(const bf16x8*)qp;
    aq[1] = *(const bf16x8*)(qp + 32);
  }

  f32x4 o[4];
#pragma unroll
  for (int et = 0; et < 4; ++et) o[et] = (f32x4){0.f, 0.f, 0.f, 0.f};
  float m_run[4], l_run[4];
#pragma unroll
  for (int r = 0; r < 4; ++r) { m_run[r] = -1e30f; l_run[r] = 0.f; }

  const int row = tid >> 2, qtr = tid & 3;   // staging coords

  for (int kt = 0; kt < 32; ++kt) {
    const int k0 = kt * 64;
    __syncthreads();
    {
      const short* kp = Kb + hbase + (size_t)(k0 + row) * 64 + qtr * 16;
      const short* vp = Vb + hbase + (size_t)(k0 + row) * 64 + qtr * 16;
      *(short8*)&K_lds[row * 72 + qtr * 16] = *(const short8*)kp;
      *(short8*)&K_lds[row * 72 + qtr * 16 + 8] = *(const short8*)(kp + 8);
      *(short8*)&V_lds[row * 72 + qtr * 16] = *(const short8*)vp;
      *(short8*)&V_lds[row * 72 + qtr * 16 + 8] = *(const short8*)(vp + 8);
    }
    __syncthreads();

    // scores: s[kc] is 16q x 16k tile, kc over 64 keys
    f32x4 s[4];
#pragma unroll
    for (int kc = 0; kc < 4; ++kc) s[kc] = (f32x4){0.f, 0.f, 0.f, 0.f};
#pragma unroll
    for (int kc = 0; kc < 4; ++kc) {
#pragma unroll
      for (int half = 0; half < 2; ++half) {
        bf16x8 bk_ = *(const bf16x8*)&K_lds[(kc * 16 + lr) * 72 + half * 32 + hi * 8];
        s[kc] = __builtin_amdgcn_mfma_f32_16x16x32_bf16(aq[half], bk_, s[kc], 0, 0, 0);
      }
    }

    // online softmax (row = hi*4+r, col = kc*16+lr)
#pragma unroll
    for (int r = 0; r < 4; ++r) {
      float mx = fmaxf(fmaxf(s[0][r], s[1][r]), fmaxf(s[2][r], s[3][r]));
      mx = fmaxf(mx, __shfl_xor(mx, 1, 16));
      mx = fmaxf(mx, __shfl_xor(mx, 2, 16));
      mx = fmaxf(mx, __shfl_xor(mx, 4, 16));
      mx = fmaxf(mx, __shfl_xor(mx, 8, 16));
      const float mn = fmaxf(m_run[r], mx);
      const float sc = __builtin_amdgcn_exp2f((m_run[r] - mn) * LOG2E);
      float sum = 0.f;
#pragma unroll
      for (int kc = 0; kc < 4; ++kc) {
        float p = __builtin_amdgcn_exp2f((s[kc][r] - mn) * LOG2E);
        s[kc][r] = p;
        sum += p;
      }
      sum += __shfl_xor(sum, 1, 16);
      sum += __shfl_xor(sum, 2, 16);
      sum += __shfl_xor(sum, 4, 16);
      sum += __shfl_xor(sum, 8, 16);
      l_run[r] = l_run[r] * sc + sum;
      m_run[r] = mn;
#pragma unroll
      for (int et = 0; et < 4; ++et) o[et][r] *= sc;
    }

    // P -> per-wave LDS (bf16)
    short* pw = &P_lds[wid][0];
#pragma unroll
    for (int kc = 0; kc < 4; ++kc)
#pragma unroll
      for (int r = 0; r < 4; ++r)
        pw[(hi * 4 + r) * 72 + kc * 16 + lr] = (short)f2bf(s[kc][r]);

    // PV: o[et] += P @ V
#pragma unroll
    for (int kk = 0; kk < 2; ++kk) {
      bf16x8 pa = *(const bf16x8*)&P_lds[wid][lr * 72 + kk * 32 + hi * 8];
#pragma unroll
      for (int et = 0; et < 4; ++et) {
        short8 vv;
#pragma unroll
        for (int j = 0; j < 8; ++j)
          vv[j] = V_lds[(kk * 32 + hi * 8 + j) * 72 + et * 16 + lr];
        o[et] = __builtin_amdgcn_mfma_f32_16x16x32_bf16(pa, __builtin_bit_cast(bf16x8, vv), o[et], 0, 0, 0);
      }
    }
  }

  // epilogue: Out[b][s][h*64+e] += o/l
  const int b = bh >> 4, h = bh & 15;
#pragma unroll
  for (int et = 0; et < 4; ++et) {
#pragma unroll
    for (int r = 0; r < 4; ++r) {
      const int sidx = q0 + wid * 16 + hi * 4 + r;
      const size_t idx = ((size_t)b * 2048 + sidx) * 1024 + h * 64 + et * 16 + lr;
      Out[idx] += o[et][r] / l_run[r];
    }
  }
}

extern "C" void kernel_launch(void* const* d_in, const int* in_sizes, int n_in,
                              void* d_out, int out_size, void* d_ws, size_t ws_size,
                              hipStream_t stream) {
  const float* x  = (const float*)d_in[0];
  const float* Wq = (const float*)d_in[1];
  const float* bq = (const float*)d_in[2];
  const float* Wk = (const float*)d_in[3];
  const float* bk = (const float*)d_in[4];
  const float* Wv = (const float*)d_in[5];
  const float* bv = (const float*)d_in[6];
  const float* Wr = (const float*)d_in[7];
  const float* br = (const float*)d_in[8];
  float* Out = (float*)d_out;

  char* ws = (char*)d_ws;
  short* Xb = (short*)(ws);                                  // 16 MiB  [8192][1024] bf16
  short* Wc = (short*)(ws + (size_t)16 * 1024 * 1024);       //  8 MiB  [4096][1024] bf16 (B^T)
  short* Qb = (short*)(ws + (size_t)24 * 1024 * 1024);       // 16 MiB  [B][H][S][E]
  short* Kb = (short*)(ws + (size_t)40 * 1024 * 1024);       // 16 MiB
  short* Vb = (short*)(ws + (size_t)56 * 1024 * 1024);       // 16 MiB  (ends at 72 MiB)

  k_cvt_x<<<8192, 256, 0, stream>>>(x, Xb);
  k_cvt_w<<<1024, 256, 0, stream>>>(Wq, Wk, Wv, Wr, Wc);
  k_gemm<<<2048, 256, 0, stream>>>(Xb, Wc, bq, bk, bv, br, Qb, Kb, Vb, Out);
  k_attn<<<2048, 256, 0, stream>>>(Qb, Kb, Vb, Out);
}

// Round 2
// 265.222 us; speedup vs baseline: 1.4898x; 1.4898x over previous
//
#include <hip/hip_runtime.h>

// MutiHeadSelfAttention: B=4,S=2048,D=1024,H=16,E=64
// cvt_x -> cvt_w -> fused QKVR GEMM -> V transpose -> flash attn (swapped-QK, bpermute P-repack)

typedef __bf16 bf16x8 __attribute__((ext_vector_type(8)));
typedef float  f32x4  __attribute__((ext_vector_type(4)));
typedef short  short8 __attribute__((ext_vector_type(8)));
typedef short  short4v __attribute__((ext_vector_type(4)));
typedef float  float4v __attribute__((ext_vector_type(4)));
typedef int    int4v  __attribute__((ext_vector_type(4)));

#define LOG2E 1.44269504088896f

__device__ __forceinline__ unsigned short f2bf(float f) {
  unsigned u = __builtin_bit_cast(unsigned, f);
  u += 0x7fffu + ((u >> 16) & 1u);   // RNE
  return (unsigned short)(u >> 16);
}

__device__ __forceinline__ unsigned pack2(float lo, float hi) {
  __bf16 a = (__bf16)lo, b = (__bf16)hi;
  unsigned short ua = __builtin_bit_cast(unsigned short, a);
  unsigned short ub = __builtin_bit_cast(unsigned short, b);
  return (unsigned)ua | ((unsigned)ub << 16);
}

// ---------------- x fp32 -> bf16 ----------------
__global__ __launch_bounds__(256) void k_cvt_x(const float* __restrict__ x,
                                               short* __restrict__ Xb) {
  const size_t i = ((size_t)blockIdx.x * 256 + threadIdx.x) * 4;
  float4v f = *(const float4v*)(x + i);
  short4v o;
  o[0] = (short)f2bf(f[0]); o[1] = (short)f2bf(f[1]);
  o[2] = (short)f2bf(f[2]); o[3] = (short)f2bf(f[3]);
  *(short4v*)(Xb + i) = o;
}

// ---------------- W [1024k][1024n] fp32 x4 -> Wc[4096 n][1024 k] bf16 (B^T) ----------------
__global__ __launch_bounds__(256) void k_cvt_w(const float* __restrict__ Wq,
                                               const float* __restrict__ Wk,
                                               const float* __restrict__ Wv,
                                               const float* __restrict__ Wr,
                                               short* __restrict__ Wc) {
  const int bid = blockIdx.x;
  const int w = bid >> 8;
  const int t = bid & 255;
  const int tr = t >> 4, tc = t & 15;
  const float* Ws = (w == 0) ? Wq : (w == 1) ? Wk : (w == 2) ? Wv : Wr;
  __shared__ float T[64][65];
  const int tx = threadIdx.x & 63, ty = threadIdx.x >> 6;
#pragma unroll
  for (int i = 0; i < 16; ++i)
    T[i * 4 + ty][tx] = Ws[(size_t)(tr * 64 + i * 4 + ty) * 1024 + tc * 64 + tx];
  __syncthreads();
#pragma unroll
  for (int i = 0; i < 16; ++i) {
    const int n = tc * 64 + i * 4 + ty;
    Wc[((size_t)w * 1024 + n) * 1024 + tr * 64 + tx] = (short)f2bf(T[tx][i * 4 + ty]);
  }
}

// ---------------- fused QKVR GEMM: C[8192][4096] = Xb @ Wc^T ----------------
__global__ __launch_bounds__(256) void k_gemm(const short* __restrict__ Xb,
                                              const short* __restrict__ Wc,
                                              const float* __restrict__ bq,
                                              const float* __restrict__ bk2,
                                              const float* __restrict__ bv,
                                              const float* __restrict__ br,
                                              short* __restrict__ Qb,
                                              short* __restrict__ Kb,
                                              short* __restrict__ Vb,
                                              float* __restrict__ Out) {
  __shared__ short As[128 * 32];
  __shared__ short Bs[128 * 32];
  const int tid = threadIdx.x, wid = tid >> 6, lane = tid & 63;
  const int lr = lane & 15, hi = lane >> 4;
  const int bm = blockIdx.x & 63, bn = blockIdx.x >> 6;
  const int m0 = bm * 128, n0 = bn * 128;
  const int wr = wid >> 1, wc = wid & 1;

  f32x4 acc[4][4] = {};

  const int c0 = wid * 2;
  const int srow = lane >> 2;
  const int scol = (lane & 3) * 8;

  for (int k0 = 0; k0 < 1024; k0 += 32) {
    __syncthreads();
    const short* a0 = Xb + (size_t)(m0 + c0 * 16 + srow) * 1024 + k0 + scol;
    const short* a1 = Xb + (size_t)(m0 + (c0 + 1) * 16 + srow) * 1024 + k0 + scol;
    const short* b0 = Wc + (size_t)(n0 + c0 * 16 + srow) * 1024 + k0 + scol;
    const short* b1 = Wc + (size_t)(n0 + (c0 + 1) * 16 + srow) * 1024 + k0 + scol;
    __builtin_amdgcn_global_load_lds((const __attribute__((address_space(1))) void*)a0,
                                     (__attribute__((address_space(3))) void*)&As[c0 * 512], 16, 0, 0);
    __builtin_amdgcn_global_load_lds((const __attribute__((address_space(1))) void*)a1,
                                     (__attribute__((address_space(3))) void*)&As[(c0 + 1) * 512], 16, 0, 0);
    __builtin_amdgcn_global_load_lds((const __attribute__((address_space(1))) void*)b0,
                                     (__attribute__((address_space(3))) void*)&Bs[c0 * 512], 16, 0, 0);
    __builtin_amdgcn_global_load_lds((const __attribute__((address_space(1))) void*)b1,
                                     (__attribute__((address_space(3))) void*)&Bs[(c0 + 1) * 512], 16, 0, 0);
    __syncthreads();

    bf16x8 af[4], bfr[4];
#pragma unroll
    for (int i = 0; i < 4; ++i)
      af[i] = *(const bf16x8*)&As[(wr * 64 + i * 16 + lr) * 32 + hi * 8];
#pragma unroll
    for (int j = 0; j < 4; ++j)
      bfr[j] = *(const bf16x8*)&Bs[(wc * 64 + j * 16 + lr) * 32 + hi * 8];
#pragma unroll
    for (int i = 0; i < 4; ++i)
#pragma unroll
      for (int j = 0; j < 4; ++j)
        acc[i][j] = __builtin_amdgcn_mfma_f32_16x16x32_bf16(af[i], bfr[j], acc[i][j], 0, 0, 0);
  }

#pragma unroll
  for (int i = 0; i < 4; ++i) {
    const int mbase = m0 + wr * 64 + i * 16 + hi * 4;
#pragma unroll
    for (int j = 0; j < 4; ++j) {
      const int n = n0 + wc * 64 + j * 16 + lr;
      const float* bp = (n < 2048) ? (n < 1024 ? bq : bk2) : (n < 3072 ? bv : br);
      const float bias = bp[n & 1023];
#pragma unroll
      for (int r = 0; r < 4; ++r) {
        float v = acc[i][j][r] + bias;
        const int m = mbase + r;
        if (n < 3072) {
          v = fmaxf(v, 0.0f);
          const int which = n >> 10;
          const int nn = n & 1023, h = nn >> 6, e = nn & 63;
          short* dst = (which == 0) ? Qb : (which == 1) ? Kb : Vb;
          const int bb = m >> 11, ss = m & 2047;
          dst[(((size_t)bb * 16 + h) * 2048 + ss) * 64 + e] = (short)f2bf(v);
        } else {
          Out[(size_t)m * 1024 + (n - 3072)] = v;
        }
      }
    }
  }
}

// ---------------- V [bh][s][64] -> Vt [bh][e][2048] ----------------
__global__ __launch_bounds__(256) void k_tr_v(const short* __restrict__ Vb,
                                              short* __restrict__ Vt) {
  __shared__ short T[64][72];
  const int bh = blockIdx.x >> 5;
  const int s0 = (blockIdx.x & 31) * 64;
  const size_t base = (size_t)bh * 2048 * 64;
  const int t = threadIdx.x;
  const int sl = t >> 2, e0 = (t & 3) * 16;
  const short* src = Vb + base + (size_t)(s0 + sl) * 64 + e0;
  *(short8*)&T[sl][e0] = *(const short8*)src;
  *(short8*)&T[sl][e0 + 8] = *(const short8*)(src + 8);
  __syncthreads();
  const int el = t >> 2, sc0 = (t & 3) * 16;
  short8 v0, v1;
#pragma unroll
  for (int j = 0; j < 8; ++j) v0[j] = T[sc0 + j][el];
#pragma unroll
  for (int j = 0; j < 8; ++j) v1[j] = T[sc0 + 8 + j][el];
  short* dst = Vt + base + (size_t)el * 2048 + s0 + sc0;
  *(short8*)dst = v0;
  *(short8*)(dst + 8) = v1;
}

// ---------------- flash attention (swapped QK^T), += into Out ----------------
// grid: 64 bh x 16 q-tiles of 128. Block: 4 waves, 32 q-rows each (2 groups of 16).
__global__ __launch_bounds__(256) void k_attn(const short* __restrict__ Qb,
                                              const short* __restrict__ Kb,
                                              const short* __restrict__ Vt,
                                              float* __restrict__ Out) {
  __shared__ __align__(16) short smem[16384];   // 32KB: K dbuf 2x8KB, Vt dbuf 2x8KB
  const int tid = threadIdx.x, wid = tid >> 6, lane = tid & 63;
  const int lr = lane & 15, hi = lane >> 4;
  const int bh = blockIdx.x >> 4;
  const int q0 = (blockIdx.x & 15) * 128;
  const size_t hb = (size_t)bh * (2048 * 64);

  // Q fragments (B-operand): lane holds Q[q = q0+wid*32+g*16+lr][e = h*32+hi*8+j]
  bf16x8 aq[2][2];
#pragma unroll
  for (int g = 0; g < 2; ++g) {
    const short* qp = Qb + hb + (size_t)(q0 + wid * 32 + g * 16 + lr) * 64 + hi * 8;
    aq[g][0] = *(const bf16x8*)qp;
    aq[g][1] = *(const bf16x8*)(qp + 32);
  }

  f32x4 o[2][4] = {};
  float m_run[2] = {-3e38f, -3e38f}, l_run[2] = {0.f, 0.f};

  const int swz = ((lane & 7) ^ (lane >> 3)) * 8;  // pre-swizzled source chunk (shorts)
  const int rlo = lane >> 3;
  const int wr0 = wid * 16;

#define STAGE(BUF, KT)                                                                              \
  {                                                                                                 \
    const int k0_ = (KT) * 64;                                                                      \
    _Pragma("unroll")                                                                               \
    for (int i_ = 0; i_ < 2; ++i_) {                                                                \
      const int rr_ = wr0 + i_ * 8;                                                                 \
      const short* ks_ = Kb + hb + (size_t)(k0_ + rr_ + rlo) * 64 + swz;                            \
      const short* vs_ = Vt + hb + (size_t)(rr_ + rlo) * 2048 + k0_ + swz;                          \
      __builtin_amdgcn_global_load_lds((const __attribute__((address_space(1))) void*)ks_,          \
          (__attribute__((address_space(3))) void*)&smem[(BUF) * 4096 + rr_ * 64], 16, 0, 0);       \
      __builtin_amdgcn_global_load_lds((const __attribute__((address_space(1))) void*)vs_,          \
          (__attribute__((address_space(3))) void*)&smem[8192 + (BUF) * 4096 + rr_ * 64], 16, 0, 0);\
    }                                                                                               \
  }

  STAGE(0, 0);
  __syncthreads();

  const int idx0 = (lr + 32 * (hi & 1)) * 4;
  const int idx1 = idx0 + 64;
  const bool hiB = (hi >= 2);

  for (int kt = 0; kt < 32; ++kt) {
    const int buf = kt & 1;
    if (kt < 31) STAGE(buf ^ 1, kt + 1);
    const short* Kl = &smem[buf * 4096];
    const short* Vl = &smem[8192 + buf * 4096];

    // S^T = K * Q^T : lane holds S[q=lr][k = kc*16 + hi*4 + r]
    f32x4 s[2][4] = {};
#pragma unroll
    for (int kc = 0; kc < 4; ++kc) {
      const int row = kc * 16 + lr;
#pragma unroll
      for (int h = 0; h < 2; ++h) {
        const int ch = ((h * 4 + hi) ^ (lr & 7)) * 8;
        bf16x8 kf = *(const bf16x8*)&Kl[row * 64 + ch];
        s[0][kc] = __builtin_amdgcn_mfma_f32_16x16x32_bf16(kf, aq[0][h], s[0][kc], 0, 0, 0);
        s[1][kc] = __builtin_amdgcn_mfma_f32_16x16x32_bf16(kf, aq[1][h], s[1][kc], 0, 0, 0);
      }
    }

    // online softmax per q-row (q = lr): in-lane 16 values + xor16/xor32
    unsigned pd[2][4][2];
#pragma unroll
    for (int g = 0; g < 2; ++g) {
      float mx = s[g][0][0];
#pragma unroll
      for (int kc = 0; kc < 4; ++kc)
#pragma unroll
        for (int r = 0; r < 4; ++r) mx = fmaxf(mx, s[g][kc][r]);
      mx = fmaxf(mx, __shfl_xor(mx, 16));
      mx = fmaxf(mx, __shfl_xor(mx, 32));
      const float mn = fmaxf(m_run[g], mx);
      const float sc = __builtin_amdgcn_exp2f((m_run[g] - mn) * LOG2E);
      m_run[g] = mn;
      float sum = 0.f;
#pragma unroll
      for (int kc = 0; kc < 4; ++kc)
#pragma unroll
        for (int r = 0; r < 4; ++r) {
          float p = __builtin_amdgcn_exp2f((s[g][kc][r] - mn) * LOG2E);
          s[g][kc][r] = p;
          sum += p;
        }
      sum += __shfl_xor(sum, 16);
      sum += __shfl_xor(sum, 32);
      l_run[g] = l_run[g] * sc + sum;
#pragma unroll
      for (int et = 0; et < 4; ++et) o[g][et] *= sc;
#pragma unroll
      for (int kc = 0; kc < 4; ++kc) {
        pd[g][kc][0] = pack2(s[g][kc][0], s[g][kc][1]);
        pd[g][kc][1] = pack2(s[g][kc][2], s[g][kc][3]);
      }
    }

    // PV: O^T = V^T * P^T. P B-frag built via ds_bpermute repack.
#pragma unroll
    for (int kk = 0; kk < 2; ++kk) {
      bf16x8 vf[4];
#pragma unroll
      for (int et = 0; et < 4; ++et) {
        const int row = et * 16 + lr;
        const int ch = ((kk * 4 + hi) ^ (lr & 7)) * 8;
        vf[et] = *(const bf16x8*)&Vl[row * 64 + ch];
      }
#pragma unroll
      for (int g = 0; g < 2; ++g) {
        const int a0 = (int)pd[g][2 * kk][0], a1 = (int)pd[g][2 * kk][1];
        const int b0 = (int)pd[g][2 * kk + 1][0], b1 = (int)pd[g][2 * kk + 1][1];
        const int w0A = __builtin_amdgcn_ds_bpermute(idx0, a0);
        const int w1A = __builtin_amdgcn_ds_bpermute(idx0, a1);
        const int w2A = __builtin_amdgcn_ds_bpermute(idx1, a0);
        const int w3A = __builtin_amdgcn_ds_bpermute(idx1, a1);
        const int w0B = __builtin_amdgcn_ds_bpermute(idx0, b0);
        const int w1B = __builtin_amdgcn_ds_bpermute(idx0, b1);
        const int w2B = __builtin_amdgcn_ds_bpermute(idx1, b0);
        const int w3B = __builtin_amdgcn_ds_bpermute(idx1, b1);
        int4v pw;
        pw[0] = hiB ? w0B : w0A;
        pw[1] = hiB ? w1B : w1A;
        pw[2] = hiB ? w2B : w2A;
        pw[3] = hiB ? w3B : w3A;
        bf16x8 pa = __builtin_bit_cast(bf16x8, pw);
#pragma unroll
        for (int et = 0; et < 4; ++et)
          o[g][et] = __builtin_amdgcn_mfma_f32_16x16x32_bf16(vf[et], pa, o[g][et], 0, 0, 0);
      }
    }
    __syncthreads();
  }

  // epilogue: lane holds O[q=lr][e=et*16+hi*4+r]; transpose via LDS, coalesced float4 RMW
  __syncthreads();
  float* Ep = (float*)smem + wid * 1024;   // 16 x 64 fp32 per wave
  const int b = bh >> 4, h = bh & 15;
  const int qr = lane >> 2, cc = lane & 3;
#pragma unroll
  for (int g = 0; g < 2; ++g) {
    const float inv = 1.0f / l_run[g];
#pragma unroll
    for (int et = 0; et < 4; ++et)
#pragma unroll
      for (int r = 0; r < 4; ++r)
        Ep[lr * 64 + et * 16 + hi * 4 + r] = o[g][et][r] * inv;
    __syncthreads();
    const size_t gb = ((size_t)b * 2048 + q0 + wid * 32 + g * 16 + qr) * 1024 + h * 64 + cc * 4;
#pragma unroll
    for (int i = 0; i < 4; ++i) {
      float4v v = *(const float4v*)&Ep[qr * 64 + cc * 4 + i * 16];
      float4v u = *(const float4v*)&Out[gb + i * 16];
      u += v;
      *(float4v*)&Out[gb + i * 16] = u;
    }
    __syncthreads();
  }
#undef STAGE
}

extern "C" void kernel_launch(void* const* d_in, const int* in_sizes, int n_in,
                              void* d_out, int out_size, void* d_ws, size_t ws_size,
                              hipStream_t stream) {
  const float* x  = (const float*)d_in[0];
  const float* Wq = (const float*)d_in[1];
  const float* bq = (const float*)d_in[2];
  const float* Wk = (const float*)d_in[3];
  const float* bk = (const float*)d_in[4];
  const float* Wv = (const float*)d_in[5];
  const float* bv = (const float*)d_in[6];
  const float* Wr = (const float*)d_in[7];
  const float* br = (const float*)d_in[8];
  float* Out = (float*)d_out;

  char* ws = (char*)d_ws;
  short* Xb = (short*)(ws);                                  // 16 MiB [8192][1024]
  short* Wc = (short*)(ws + (size_t)16 * 1024 * 1024);       //  8 MiB [4096][1024]
  short* Qb = (short*)(ws + (size_t)24 * 1024 * 1024);       // 16 MiB [B][H][S][E]
  short* Kb = (short*)(ws + (size_t)40 * 1024 * 1024);       // 16 MiB
  short* Vb = (short*)(ws + (size_t)56 * 1024 * 1024);       // 16 MiB
  short* Vt = (short*)(ws);                                  // 16 MiB [B][H][E][S] (reuses Xb)

  k_cvt_x<<<8192, 256, 0, stream>>>(x, Xb);
  k_cvt_w<<<1024, 256, 0, stream>>>(Wq, Wk, Wv, Wr, Wc);
  k_gemm<<<2048, 256, 0, stream>>>(Xb, Wc, bq, bk, bv, br, Qb, Kb, Vb, Out);
  k_tr_v<<<2048, 256, 0, stream>>>(Vb, Vt);
  k_attn<<<1024, 256, 0, stream>>>(Qb, Kb, Vt, Out);
}

// Round 3
// 240.124 us; speedup vs baseline: 1.6455x; 1.1045x over previous
//
#include <hip/hip_runtime.h>

// MutiHeadSelfAttention: B=4,S=2048,D=1024,H=16,E=64
// cvt_x -> cvt_w -> fused QKVR GEMM -> V transpose (key-permuted) -> flash attn
// Attn: swapped QK^T; PV B-fragment is lane-local via key permutation baked into Vt.

typedef __bf16 bf16x8 __attribute__((ext_vector_type(8)));
typedef float  f32x4  __attribute__((ext_vector_type(4)));
typedef short  short8 __attribute__((ext_vector_type(8)));
typedef short  short4v __attribute__((ext_vector_type(4)));
typedef float  float4v __attribute__((ext_vector_type(4)));
typedef int    int4v  __attribute__((ext_vector_type(4)));

#define LOG2E 1.44269504088896f

__device__ __forceinline__ unsigned short f2bf(float f) {
  unsigned u = __builtin_bit_cast(unsigned, f);
  u += 0x7fffu + ((u >> 16) & 1u);   // RNE
  return (unsigned short)(u >> 16);
}

__device__ __forceinline__ unsigned pack2(float lo, float hi) {
  __bf16 a = (__bf16)lo, b = (__bf16)hi;
  unsigned short ua = __builtin_bit_cast(unsigned short, a);
  unsigned short ub = __builtin_bit_cast(unsigned short, b);
  return (unsigned)ua | ((unsigned)ub << 16);
}

// ---------------- x fp32 -> bf16 ----------------
__global__ __launch_bounds__(256) void k_cvt_x(const float* __restrict__ x,
                                               short* __restrict__ Xb) {
  const size_t i = ((size_t)blockIdx.x * 256 + threadIdx.x) * 4;
  float4v f = *(const float4v*)(x + i);
  short4v o;
  o[0] = (short)f2bf(f[0]); o[1] = (short)f2bf(f[1]);
  o[2] = (short)f2bf(f[2]); o[3] = (short)f2bf(f[3]);
  *(short4v*)(Xb + i) = o;
}

// ---------------- W [1024k][1024n] fp32 x4 -> Wc[4096 n][1024 k] bf16 (B^T) ----------------
__global__ __launch_bounds__(256) void k_cvt_w(const float* __restrict__ Wq,
                                               const float* __restrict__ Wk,
                                               const float* __restrict__ Wv,
                                               const float* __restrict__ Wr,
                                               short* __restrict__ Wc) {
  const int bid = blockIdx.x;
  const int w = bid >> 8;
  const int t = bid & 255;
  const int tr = t >> 4, tc = t & 15;
  const float* Ws = (w == 0) ? Wq : (w == 1) ? Wk : (w == 2) ? Wv : Wr;
  __shared__ float T[64][65];
  const int tx = threadIdx.x & 63, ty = threadIdx.x >> 6;
#pragma unroll
  for (int i = 0; i < 16; ++i)
    T[i * 4 + ty][tx] = Ws[(size_t)(tr * 64 + i * 4 + ty) * 1024 + tc * 64 + tx];
  __syncthreads();
#pragma unroll
  for (int i = 0; i < 16; ++i) {
    const int n = tc * 64 + i * 4 + ty;
    Wc[((size_t)w * 1024 + n) * 1024 + tr * 64 + tx] = (short)f2bf(T[tx][i * 4 + ty]);
  }
}

// ---------------- fused QKVR GEMM: C[8192][4096] = Xb @ Wc^T ----------------
__global__ __launch_bounds__(256) void k_gemm(const short* __restrict__ Xb,
                                              const short* __restrict__ Wc,
                                              const float* __restrict__ bq,
                                              const float* __restrict__ bk2,
                                              const float* __restrict__ bv,
                                              const float* __restrict__ br,
                                              short* __restrict__ Qb,
                                              short* __restrict__ Kb,
                                              short* __restrict__ Vb,
                                              float* __restrict__ Out) {
  __shared__ short As[128 * 32];
  __shared__ short Bs[128 * 32];
  const int tid = threadIdx.x, wid = tid >> 6, lane = tid & 63;
  const int lr = lane & 15, hi = lane >> 4;
  const int bm = blockIdx.x & 63, bn = blockIdx.x >> 6;
  const int m0 = bm * 128, n0 = bn * 128;
  const int wr = wid >> 1, wc = wid & 1;

  f32x4 acc[4][4] = {};

  const int c0 = wid * 2;
  const int srow = lane >> 2;
  const int scol = (lane & 3) * 8;

  for (int k0 = 0; k0 < 1024; k0 += 32) {
    __syncthreads();
    const short* a0 = Xb + (size_t)(m0 + c0 * 16 + srow) * 1024 + k0 + scol;
    const short* a1 = Xb + (size_t)(m0 + (c0 + 1) * 16 + srow) * 1024 + k0 + scol;
    const short* b0 = Wc + (size_t)(n0 + c0 * 16 + srow) * 1024 + k0 + scol;
    const short* b1 = Wc + (size_t)(n0 + (c0 + 1) * 16 + srow) * 1024 + k0 + scol;
    __builtin_amdgcn_global_load_lds((const __attribute__((address_space(1))) void*)a0,
                                     (__attribute__((address_space(3))) void*)&As[c0 * 512], 16, 0, 0);
    __builtin_amdgcn_global_load_lds((const __attribute__((address_space(1))) void*)a1,
                                     (__attribute__((address_space(3))) void*)&As[(c0 + 1) * 512], 16, 0, 0);
    __builtin_amdgcn_global_load_lds((const __attribute__((address_space(1))) void*)b0,
                                     (__attribute__((address_space(3))) void*)&Bs[c0 * 512], 16, 0, 0);
    __builtin_amdgcn_global_load_lds((const __attribute__((address_space(1))) void*)b1,
                                     (__attribute__((address_space(3))) void*)&Bs[(c0 + 1) * 512], 16, 0, 0);
    __syncthreads();

    bf16x8 af[4], bfr[4];
#pragma unroll
    for (int i = 0; i < 4; ++i)
      af[i] = *(const bf16x8*)&As[(wr * 64 + i * 16 + lr) * 32 + hi * 8];
#pragma unroll
    for (int j = 0; j < 4; ++j)
      bfr[j] = *(const bf16x8*)&Bs[(wc * 64 + j * 16 + lr) * 32 + hi * 8];
#pragma unroll
    for (int i = 0; i < 4; ++i)
#pragma unroll
      for (int j = 0; j < 4; ++j)
        acc[i][j] = __builtin_amdgcn_mfma_f32_16x16x32_bf16(af[i], bfr[j], acc[i][j], 0, 0, 0);
  }

#pragma unroll
  for (int i = 0; i < 4; ++i) {
    const int mbase = m0 + wr * 64 + i * 16 + hi * 4;
#pragma unroll
    for (int j = 0; j < 4; ++j) {
      const int n = n0 + wc * 64 + j * 16 + lr;
      const float* bp = (n < 2048) ? (n < 1024 ? bq : bk2) : (n < 3072 ? bv : br);
      const float bias = bp[n & 1023];
#pragma unroll
      for (int r = 0; r < 4; ++r) {
        float v = acc[i][j][r] + bias;
        const int m = mbase + r;
        if (n < 3072) {
          v = fmaxf(v, 0.0f);
          const int which = n >> 10;
          const int nn = n & 1023, h = nn >> 6, e = nn & 63;
          short* dst = (which == 0) ? Qb : (which == 1) ? Kb : Vb;
          const int bb = m >> 11, ss = m & 2047;
          dst[(((size_t)bb * 16 + h) * 2048 + ss) * 64 + e] = (short)f2bf(v);
        } else {
          Out[(size_t)m * 1024 + (n - 3072)] = v;
        }
      }
    }
  }
}

// ---------------- V [bh][s][64] -> Vt [bh][e][2048], key-permuted within 32-blocks ----
// Position sigma in each 32-block holds key pi(sigma) = (sigma&4 ? 16:0) + (sigma>>3)*4 + (sigma&3).
// This makes the attn PV B-fragment lane-local (no cross-lane P exchange).
__global__ __launch_bounds__(256) void k_tr_v(const short* __restrict__ Vb,
                                              short* __restrict__ Vt) {
  __shared__ short T[64][72];
  const int bh = blockIdx.x >> 5;
  const int s0 = (blockIdx.x & 31) * 64;
  const size_t base = (size_t)bh * 2048 * 64;
  const int t = threadIdx.x;
  const int sl = t >> 2, e0 = (t & 3) * 16;
  const short* src = Vb + base + (size_t)(s0 + sl) * 64 + e0;
  *(short8*)&T[sl][e0] = *(const short8*)src;
  *(short8*)&T[sl][e0 + 8] = *(const short8*)(src + 8);
  __syncthreads();
  const int el = t >> 2, sc0 = (t & 3) * 16;
  const int b32 = sc0 & ~31;
  const int s_off = sc0 & 31;
  short tmp[16];
#pragma unroll
  for (int j = 0; j < 16; ++j) {
    const int sig = s_off + j;
    const int key = ((sig & 4) ? 16 : 0) + ((sig >> 3) << 2) + (sig & 3);
    tmp[j] = T[b32 + key][el];
  }
  short* dst = Vt + base + (size_t)el * 2048 + s0 + sc0;
  *(short8*)dst = *(const short8*)&tmp[0];
  *(short8*)(dst + 8) = *(const short8*)&tmp[8];
}

// ---------------- flash attention (swapped QK^T), += into Out ----------------
// grid: 1024 (XCD-swizzled): 64 bh x 16 q-tiles of 128. Block: 4 waves, 32 q-rows each.
__global__ __launch_bounds__(256) void k_attn(const short* __restrict__ Qb,
                                              const short* __restrict__ Kb,
                                              const short* __restrict__ Vt,
                                              float* __restrict__ Out) {
  __shared__ __align__(16) short smem[16384];   // 32KB: K dbuf 2x8KB, Vt dbuf 2x8KB
  const int tid = threadIdx.x, wid = tid >> 6, lane = tid & 63;
  const int lr = lane & 15, hi = lane >> 4;
  const int bid = ((blockIdx.x & 7) << 7) | (blockIdx.x >> 3);  // XCD-bijective swizzle
  const int bh = bid >> 4;
  const int q0 = (bid & 15) * 128;
  const size_t hb = (size_t)bh * (2048 * 64);

  // Q fragments (B-operand): lane holds Q[q = q0+wid*32+g*16+lr][e = h*32+hi*8+j]
  bf16x8 aq[2][2];
#pragma unroll
  for (int g = 0; g < 2; ++g) {
    const short* qp = Qb + hb + (size_t)(q0 + wid * 32 + g * 16 + lr) * 64 + hi * 8;
    aq[g][0] = *(const bf16x8*)qp;
    aq[g][1] = *(const bf16x8*)(qp + 32);
  }

  f32x4 o[2][4] = {};
  float m_run[2] = {-3e38f, -3e38f}, l_run[2] = {0.f, 0.f};

  const int swz = ((lane & 7) ^ (lane >> 3)) * 8;  // pre-swizzled source chunk (shorts)
  const int rlo = lane >> 3;
  const int wr0 = wid * 16;

#define STAGE(BUF, KT)                                                                              \
  {                                                                                                 \
    const int k0_ = (KT) * 64;                                                                      \
    _Pragma("unroll")                                                                               \
    for (int i_ = 0; i_ < 2; ++i_) {                                                                \
      const int rr_ = wr0 + i_ * 8;                                                                 \
      const short* ks_ = Kb + hb + (size_t)(k0_ + rr_ + rlo) * 64 + swz;                            \
      const short* vs_ = Vt + hb + (size_t)(rr_ + rlo) * 2048 + k0_ + swz;                          \
      __builtin_amdgcn_global_load_lds((const __attribute__((address_space(1))) void*)ks_,          \
          (__attribute__((address_space(3))) void*)&smem[(BUF) * 4096 + rr_ * 64], 16, 0, 0);       \
      __builtin_amdgcn_global_load_lds((const __attribute__((address_space(1))) void*)vs_,          \
          (__attribute__((address_space(3))) void*)&smem[8192 + (BUF) * 4096 + rr_ * 64], 16, 0, 0);\
    }                                                                                               \
  }

  STAGE(0, 0);
  __syncthreads();

  for (int kt = 0; kt < 32; ++kt) {
    const int buf = kt & 1;
    if (kt < 31) STAGE(buf ^ 1, kt + 1);
    const short* Kl = &smem[buf * 4096];
    const short* Vl = &smem[8192 + buf * 4096];

    // S^T = K * Q^T : lane holds S[q=lr][k = kc*16 + hi*4 + r]
    f32x4 s[2][4] = {};
#pragma unroll
    for (int kc = 0; kc < 4; ++kc) {
      const int row = kc * 16 + lr;
#pragma unroll
      for (int h = 0; h < 2; ++h) {
        const int ch = ((h * 4 + hi) ^ (lr & 7)) * 8;
        bf16x8 kf = *(const bf16x8*)&Kl[row * 64 + ch];
        s[0][kc] = __builtin_amdgcn_mfma_f32_16x16x32_bf16(kf, aq[0][h], s[0][kc], 0, 0, 0);
        s[1][kc] = __builtin_amdgcn_mfma_f32_16x16x32_bf16(kf, aq[1][h], s[1][kc], 0, 0, 0);
      }
    }

    // online softmax per q-row (q = lr); l kept lane-partial (reduced in epilogue)
    unsigned pd[2][4][2];
#pragma unroll
    for (int g = 0; g < 2; ++g) {
      float mx = fmaxf(fmaxf(s[g][0][0], s[g][0][1]), fmaxf(s[g][0][2], s[g][0][3]));
#pragma unroll
      for (int kc = 1; kc < 4; ++kc)
        mx = fmaxf(mx, fmaxf(fmaxf(s[g][kc][0], s[g][kc][1]), fmaxf(s[g][kc][2], s[g][kc][3])));
      mx = fmaxf(mx, __shfl_xor(mx, 16));
      mx = fmaxf(mx, __shfl_xor(mx, 32));
      float sum = 0.f;
      if (__all(mx - m_run[g] <= 8.0f)) {          // defer-max: skip rescale (P <= e^8)
        const float mb = m_run[g];
#pragma unroll
        for (int kc = 0; kc < 4; ++kc) {
          float p0 = __builtin_amdgcn_exp2f((s[g][kc][0] - mb) * LOG2E);
          float p1 = __builtin_amdgcn_exp2f((s[g][kc][1] - mb) * LOG2E);
          float p2 = __builtin_amdgcn_exp2f((s[g][kc][2] - mb) * LOG2E);
          float p3 = __builtin_amdgcn_exp2f((s[g][kc][3] - mb) * LOG2E);
          sum += (p0 + p1) + (p2 + p3);
          pd[g][kc][0] = pack2(p0, p1);
          pd[g][kc][1] = pack2(p2, p3);
        }
        l_run[g] += sum;
      } else {
        const float mn = fmaxf(m_run[g], mx);
        const float sc = __builtin_amdgcn_exp2f((m_run[g] - mn) * LOG2E);
        m_run[g] = mn;
#pragma unroll
        for (int kc = 0; kc < 4; ++kc) {
          float p0 = __builtin_amdgcn_exp2f((s[g][kc][0] - mn) * LOG2E);
          float p1 = __builtin_amdgcn_exp2f((s[g][kc][1] - mn) * LOG2E);
          float p2 = __builtin_amdgcn_exp2f((s[g][kc][2] - mn) * LOG2E);
          float p3 = __builtin_amdgcn_exp2f((s[g][kc][3] - mn) * LOG2E);
          sum += (p0 + p1) + (p2 + p3);
          pd[g][kc][0] = pack2(p0, p1);
          pd[g][kc][1] = pack2(p2, p3);
        }
        l_run[g] = l_run[g] * sc + sum;
#pragma unroll
        for (int et = 0; et < 4; ++et) o[g][et] *= sc;
      }
    }

    // PV: O^T = V^T * P^T. Key permutation in Vt makes P B-frag lane-local.
#pragma unroll
    for (int kk = 0; kk < 2; ++kk) {
      bf16x8 vf[4];
#pragma unroll
      for (int et = 0; et < 4; ++et) {
        const int row = et * 16 + lr;
        const int ch = ((kk * 4 + hi) ^ (lr & 7)) * 8;
        vf[et] = *(const bf16x8*)&Vl[row * 64 + ch];
      }
#pragma unroll
      for (int g = 0; g < 2; ++g) {
        int4v pw;
        pw[0] = (int)pd[g][2 * kk][0];
        pw[1] = (int)pd[g][2 * kk][1];
        pw[2] = (int)pd[g][2 * kk + 1][0];
        pw[3] = (int)pd[g][2 * kk + 1][1];
        bf16x8 pa = __builtin_bit_cast(bf16x8, pw);
#pragma unroll
        for (int et = 0; et < 4; ++et)
          o[g][et] = __builtin_amdgcn_mfma_f32_16x16x32_bf16(vf[et], pa, o[g][et], 0, 0, 0);
      }
    }
    __syncthreads();
  }

  // epilogue: reduce l across the 4-lane q-group, transpose via padded LDS, float4 RMW
  __syncthreads();
  float* Ep = (float*)smem + wid * 1088;   // 16 x 68 fp32 per wave (padded stride)
  const int b = bh >> 4, h = bh & 15;
  const int qr = lane >> 2, cc = lane & 3;
#pragma unroll
  for (int g = 0; g < 2; ++g) {
    float lt = l_run[g];
    lt += __shfl_xor(lt, 16);
    lt += __shfl_xor(lt, 32);
    const float inv = 1.0f / lt;
#pragma unroll
    for (int et = 0; et < 4; ++et)
#pragma unroll
      for (int r = 0; r < 4; ++r)
        Ep[lr * 68 + et * 16 + hi * 4 + r] = o[g][et][r] * inv;
    __syncthreads();
    const size_t gb = ((size_t)b * 2048 + q0 + wid * 32 + g * 16 + qr) * 1024 + h * 64 + cc * 4;
#pragma unroll
    for (int i = 0; i < 4; ++i) {
      float4v v = *(const float4v*)&Ep[qr * 68 + cc * 4 + i * 16];
      float4v u = *(const float4v*)&Out[gb + i * 16];
      u += v;
      *(float4v*)&Out[gb + i * 16] = u;
    }
    __syncthreads();
  }
#undef STAGE
}

extern "C" void kernel_launch(void* const* d_in, const int* in_sizes, int n_in,
                              void* d_out, int out_size, void* d_ws, size_t ws_size,
                              hipStream_t stream) {
  const float* x  = (const float*)d_in[0];
  const float* Wq = (const float*)d_in[1];
  const float* bq = (const float*)d_in[2];
  const float* Wk = (const float*)d_in[3];
  const float* bk = (const float*)d_in[4];
  const float* Wv = (const float*)d_in[5];
  const float* bv = (const float*)d_in[6];
  const float* Wr = (const float*)d_in[7];
  const float* br = (const float*)d_in[8];
  float* Out = (float*)d_out;

  char* ws = (char*)d_ws;
  short* Xb = (short*)(ws);                                  // 16 MiB [8192][1024]
  short* Wc = (short*)(ws + (size_t)16 * 1024 * 1024);       //  8 MiB [4096][1024]
  short* Qb = (short*)(ws + (size_t)24 * 1024 * 1024);       // 16 MiB [B][H][S][E]
  short* Kb = (short*)(ws + (size_t)40 * 1024 * 1024);       // 16 MiB
  short* Vb = (short*)(ws + (size_t)56 * 1024 * 1024);       // 16 MiB
  short* Vt = (short*)(ws);                                  // 16 MiB [B][H][E][S'] (reuses Xb)

  k_cvt_x<<<8192, 256, 0, stream>>>(x, Xb);
  k_cvt_w<<<1024, 256, 0, stream>>>(Wq, Wk, Wv, Wr, Wc);
  k_gemm<<<2048, 256, 0, stream>>>(Xb, Wc, bq, bk, bv, br, Qb, Kb, Vb, Out);
  k_tr_v<<<2048, 256, 0, stream>>>(Vb, Vt);
  k_attn<<<1024, 256, 0, stream>>>(Qb, Kb, Vt, Out);
}

// Round 4
// 237.303 us; speedup vs baseline: 1.6650x; 1.0119x over previous
//
#include <hip/hip_runtime.h>

// MutiHeadSelfAttention: B=4,S=2048,D=1024,H=16,E=64
// cvt_x -> cvt_w -> fused QKVR GEMM -> V transpose (key-permuted) -> flash attn
// Attn: swapped QK^T; PV B-fragment lane-local via key permutation baked into Vt.
// R4: q-tile 64 (grid 2048, 5 waves/SIMD), induction-pointer staging, immediate-offset
//     ds_reads, zero-quad MFMA init, unified defer-max softmax path.

typedef __bf16 bf16x8 __attribute__((ext_vector_type(8)));
typedef float  f32x4  __attribute__((ext_vector_type(4)));
typedef short  short8 __attribute__((ext_vector_type(8)));
typedef short  short4v __attribute__((ext_vector_type(4)));
typedef float  float4v __attribute__((ext_vector_type(4)));
typedef int    int4v  __attribute__((ext_vector_type(4)));

#define LOG2E 1.44269504088896f

__device__ __forceinline__ unsigned short f2bf(float f) {
  unsigned u = __builtin_bit_cast(unsigned, f);
  u += 0x7fffu + ((u >> 16) & 1u);   // RNE
  return (unsigned short)(u >> 16);
}

__device__ __forceinline__ unsigned pack2(float lo, float hi) {
  __bf16 a = (__bf16)lo, b = (__bf16)hi;
  unsigned short ua = __builtin_bit_cast(unsigned short, a);
  unsigned short ub = __builtin_bit_cast(unsigned short, b);
  return (unsigned)ua | ((unsigned)ub << 16);
}

// ---------------- x fp32 -> bf16 ----------------
__global__ __launch_bounds__(256) void k_cvt_x(const float* __restrict__ x,
                                               short* __restrict__ Xb) {
  const size_t i = ((size_t)blockIdx.x * 256 + threadIdx.x) * 4;
  float4v f = *(const float4v*)(x + i);
  short4v o;
  o[0] = (short)f2bf(f[0]); o[1] = (short)f2bf(f[1]);
  o[2] = (short)f2bf(f[2]); o[3] = (short)f2bf(f[3]);
  *(short4v*)(Xb + i) = o;
}

// ---------------- W [1024k][1024n] fp32 x4 -> Wc[4096 n][1024 k] bf16 (B^T) ----------------
__global__ __launch_bounds__(256) void k_cvt_w(const float* __restrict__ Wq,
                                               const float* __restrict__ Wk,
                                               const float* __restrict__ Wv,
                                               const float* __restrict__ Wr,
                                               short* __restrict__ Wc) {
  const int bid = blockIdx.x;
  const int w = bid >> 8;
  const int t = bid & 255;
  const int tr = t >> 4, tc = t & 15;
  const float* Ws = (w == 0) ? Wq : (w == 1) ? Wk : (w == 2) ? Wv : Wr;
  __shared__ float T[64][65];
  const int tx = threadIdx.x & 63, ty = threadIdx.x >> 6;
#pragma unroll
  for (int i = 0; i < 16; ++i)
    T[i * 4 + ty][tx] = Ws[(size_t)(tr * 64 + i * 4 + ty) * 1024 + tc * 64 + tx];
  __syncthreads();
#pragma unroll
  for (int i = 0; i < 16; ++i) {
    const int n = tc * 64 + i * 4 + ty;
    Wc[((size_t)w * 1024 + n) * 1024 + tr * 64 + tx] = (short)f2bf(T[tx][i * 4 + ty]);
  }
}

// ---------------- fused QKVR GEMM: C[8192][4096] = Xb @ Wc^T ----------------
__global__ __launch_bounds__(256) void k_gemm(const short* __restrict__ Xb,
                                              const short* __restrict__ Wc,
                                              const float* __restrict__ bq,
                                              const float* __restrict__ bk2,
                                              const float* __restrict__ bv,
                                              const float* __restrict__ br,
                                              short* __restrict__ Qb,
                                              short* __restrict__ Kb,
                                              short* __restrict__ Vb,
                                              float* __restrict__ Out) {
  __shared__ short As[128 * 32];
  __shared__ short Bs[128 * 32];
  const int tid = threadIdx.x, wid = tid >> 6, lane = tid & 63;
  const int lr = lane & 15, hi = lane >> 4;
  const int bm = blockIdx.x & 63, bn = blockIdx.x >> 6;
  const int m0 = bm * 128, n0 = bn * 128;
  const int wr = wid >> 1, wc = wid & 1;

  f32x4 acc[4][4] = {};

  const int c0 = wid * 2;
  const int srow = lane >> 2;
  const int scol = (lane & 3) * 8;

  for (int k0 = 0; k0 < 1024; k0 += 32) {
    __syncthreads();
    const short* a0 = Xb + (size_t)(m0 + c0 * 16 + srow) * 1024 + k0 + scol;
    const short* a1 = Xb + (size_t)(m0 + (c0 + 1) * 16 + srow) * 1024 + k0 + scol;
    const short* b0 = Wc + (size_t)(n0 + c0 * 16 + srow) * 1024 + k0 + scol;
    const short* b1 = Wc + (size_t)(n0 + (c0 + 1) * 16 + srow) * 1024 + k0 + scol;
    __builtin_amdgcn_global_load_lds((const __attribute__((address_space(1))) void*)a0,
                                     (__attribute__((address_space(3))) void*)&As[c0 * 512], 16, 0, 0);
    __builtin_amdgcn_global_load_lds((const __attribute__((address_space(1))) void*)a1,
                                     (__attribute__((address_space(3))) void*)&As[(c0 + 1) * 512], 16, 0, 0);
    __builtin_amdgcn_global_load_lds((const __attribute__((address_space(1))) void*)b0,
                                     (__attribute__((address_space(3))) void*)&Bs[c0 * 512], 16, 0, 0);
    __builtin_amdgcn_global_load_lds((const __attribute__((address_space(1))) void*)b1,
                                     (__attribute__((address_space(3))) void*)&Bs[(c0 + 1) * 512], 16, 0, 0);
    __syncthreads();

    bf16x8 af[4], bfr[4];
#pragma unroll
    for (int i = 0; i < 4; ++i)
      af[i] = *(const bf16x8*)&As[(wr * 64 + i * 16 + lr) * 32 + hi * 8];
#pragma unroll
    for (int j = 0; j < 4; ++j)
      bfr[j] = *(const bf16x8*)&Bs[(wc * 64 + j * 16 + lr) * 32 + hi * 8];
#pragma unroll
    for (int i = 0; i < 4; ++i)
#pragma unroll
      for (int j = 0; j < 4; ++j)
        acc[i][j] = __builtin_amdgcn_mfma_f32_16x16x32_bf16(af[i], bfr[j], acc[i][j], 0, 0, 0);
  }

#pragma unroll
  for (int i = 0; i < 4; ++i) {
    const int mbase = m0 + wr * 64 + i * 16 + hi * 4;
#pragma unroll
    for (int j = 0; j < 4; ++j) {
      const int n = n0 + wc * 64 + j * 16 + lr;
      const float* bp = (n < 2048) ? (n < 1024 ? bq : bk2) : (n < 3072 ? bv : br);
      const float bias = bp[n & 1023];
#pragma unroll
      for (int r = 0; r < 4; ++r) {
        float v = acc[i][j][r] + bias;
        const int m = mbase + r;
        if (n < 3072) {
          v = fmaxf(v, 0.0f);
          const int which = n >> 10;
          const int nn = n & 1023, h = nn >> 6, e = nn & 63;
          short* dst = (which == 0) ? Qb : (which == 1) ? Kb : Vb;
          const int bb = m >> 11, ss = m & 2047;
          dst[(((size_t)bb * 16 + h) * 2048 + ss) * 64 + e] = (short)f2bf(v);
        } else {
          Out[(size_t)m * 1024 + (n - 3072)] = v;
        }
      }
    }
  }
}

// ---------------- V [bh][s][64] -> Vt [bh][e][2048], key-permuted within 32-blocks ----
// Position sigma holds key pi(sigma) = (sigma&4 ? 16:0) + (sigma>>3)*4 + (sigma&3).
__global__ __launch_bounds__(256) void k_tr_v(const short* __restrict__ Vb,
                                              short* __restrict__ Vt) {
  __shared__ short T[64][72];
  const int bh = blockIdx.x >> 5;
  const int s0 = (blockIdx.x & 31) * 64;
  const size_t base = (size_t)bh * 2048 * 64;
  const int t = threadIdx.x;
  const int sl = t >> 2, e0 = (t & 3) * 16;
  const short* src = Vb + base + (size_t)(s0 + sl) * 64 + e0;
  *(short8*)&T[sl][e0] = *(const short8*)src;
  *(short8*)&T[sl][e0 + 8] = *(const short8*)(src + 8);
  __syncthreads();
  const int el = t >> 2, sc0 = (t & 3) * 16;
  const int b32 = sc0 & ~31;
  const int s_off = sc0 & 31;
  short tmp[16];
#pragma unroll
  for (int j = 0; j < 16; ++j) {
    const int sig = s_off + j;
    const int key = ((sig & 4) ? 16 : 0) + ((sig >> 3) << 2) + (sig & 3);
    tmp[j] = T[b32 + key][el];
  }
  short* dst = Vt + base + (size_t)el * 2048 + s0 + sc0;
  *(short8*)dst = *(const short8*)&tmp[0];
  *(short8*)(dst + 8) = *(const short8*)&tmp[8];
}

// ---------------- flash attention (swapped QK^T), += into Out ----------------
// grid: 2048 (XCD-swizzled): 64 bh x 32 q-tiles of 64. Block: 4 waves, 16 q-rows each.
__global__ __launch_bounds__(256) void k_attn(const short* __restrict__ Qb,
                                              const short* __restrict__ Kb,
                                              const short* __restrict__ Vt,
                                              float* __restrict__ Out) {
  __shared__ __align__(16) short smem[16384];   // 32KB: K dbuf 2x8KB @0, V dbuf 2x8KB @8192
  char* const sb = (char*)smem;
  const int tid = threadIdx.x, wid = tid >> 6, lane = tid & 63;
  const int lr = lane & 15, hi = lane >> 4;
  const int bid = ((blockIdx.x & 7) << 8) | (blockIdx.x >> 3);  // XCD-bijective swizzle
  const int bh = bid >> 5;
  const int q0 = (bid & 31) * 64;
  const size_t hb = (size_t)bh * (2048 * 64);

  // Q fragments (B-operand): lane holds Q[q = q0+wid*16+lr][e = h*32+hi*8+j]
  const short* qp = Qb + hb + (size_t)(q0 + wid * 16 + lr) * 64 + hi * 8;
  const bf16x8 aq0 = *(const bf16x8*)qp;
  const bf16x8 aq1 = *(const bf16x8*)(qp + 32);

  f32x4 o[4] = {};
  float m_run = -3e38f, l_run = 0.f;

  // staging: pre-swizzled source chunk; induction pointers (no per-kt mul)
  const int swz = ((lane & 7) ^ (lane >> 3)) * 8;
  const int rlo = lane >> 3;
  const int wr0 = wid * 16;
  const short* kp0 = Kb + hb + (size_t)(wr0 + rlo) * 64 + swz;
  const short* kp1 = kp0 + 8 * 64;
  const short* vp0 = Vt + hb + (size_t)(wr0 + rlo) * 2048 + swz;
  const short* vp1 = vp0 + 8 * 2048;

  // per-lane LDS read bases (bytes); all 16 ds_reads/kt use compile-time immediates
  const int vb0 = (lr * 64 + ((hi ^ (lr & 7)) << 3)) * 2;
  const int vb1 = vb0 ^ 64;

#define GLL(SRC, LDSOFF)                                                                   \
  __builtin_amdgcn_global_load_lds((const __attribute__((address_space(1))) void*)(SRC),   \
      (__attribute__((address_space(3))) void*)(sb + (LDSOFF)), 16, 0, 0)

  // initial stage -> buf 0
  GLL(kp0, wr0 * 128);
  GLL(kp1, wr0 * 128 + 1024);
  GLL(vp0, 16384 + wr0 * 128);
  GLL(vp1, 16384 + wr0 * 128 + 1024);
  kp0 += 4096; kp1 += 4096; vp0 += 64; vp1 += 64;
  __syncthreads();

#pragma unroll 2
  for (int kt = 0; kt < 32; ++kt) {
    const int buf = kt & 1;
    if (kt < 31) {
      const int d = (buf ^ 1) * 8192 + wr0 * 128;
      GLL(kp0, d);
      GLL(kp1, d + 1024);
      GLL(vp0, 16384 + d);
      GLL(vp1, 16384 + d + 1024);
    }
    kp0 += 4096; kp1 += 4096; vp0 += 64; vp1 += 64;

    // S^T = K * Q^T : lane holds S[q=lr][k = kc*16 + hi*4 + r]
    f32x4 s[4];
#pragma unroll
    for (int kc = 0; kc < 4; ++kc) {
      const bf16x8 kf0 = *(const bf16x8*)(sb + (vb0 + buf * 8192 + kc * 2048));
      const bf16x8 kf1 = *(const bf16x8*)(sb + (vb1 + buf * 8192 + kc * 2048));
      f32x4 t = __builtin_amdgcn_mfma_f32_16x16x32_bf16(kf0, aq0, (f32x4){0.f, 0.f, 0.f, 0.f}, 0, 0, 0);
      s[kc] = __builtin_amdgcn_mfma_f32_16x16x32_bf16(kf1, aq1, t, 0, 0, 0);
    }

    // online softmax per q-row (q = lr); l lane-partial (reduced in epilogue)
    float mx = fmaxf(fmaxf(fmaxf(s[0][0], s[0][1]), fmaxf(s[0][2], s[0][3])),
                     fmaxf(fmaxf(s[1][0], s[1][1]), fmaxf(s[1][2], s[1][3])));
    mx = fmaxf(mx, fmaxf(fmaxf(fmaxf(s[2][0], s[2][1]), fmaxf(s[2][2], s[2][3])),
                         fmaxf(fmaxf(s[3][0], s[3][1]), fmaxf(s[3][2], s[3][3]))));
    mx = fmaxf(mx, __shfl_xor(mx, 16));
    mx = fmaxf(mx, __shfl_xor(mx, 32));

    if (!__all(mx - m_run <= 8.0f)) {       // rare rescale path
      const float mn = fmaxf(m_run, mx);
      const float sc = __builtin_amdgcn_exp2f((m_run - mn) * LOG2E);
      m_run = mn;
      l_run *= sc;
#pragma unroll
      for (int et = 0; et < 4; ++et) o[et] *= sc;
    }

    int4v pw[2];
    float sum = 0.f;
    {
      const float mb = m_run;
#pragma unroll
      for (int kc = 0; kc < 4; ++kc) {
        const float p0 = __builtin_amdgcn_exp2f((s[kc][0] - mb) * LOG2E);
        const float p1 = __builtin_amdgcn_exp2f((s[kc][1] - mb) * LOG2E);
        const float p2 = __builtin_amdgcn_exp2f((s[kc][2] - mb) * LOG2E);
        const float p3 = __builtin_amdgcn_exp2f((s[kc][3] - mb) * LOG2E);
        sum += (p0 + p1) + (p2 + p3);
        pw[kc >> 1][(kc & 1) * 2] = (int)pack2(p0, p1);
        pw[kc >> 1][(kc & 1) * 2 + 1] = (int)pack2(p2, p3);
      }
    }
    l_run += sum;

    // PV: O^T = V^T * P^T (key permutation in Vt makes pw the exact B-fragment)
#pragma unroll
    for (int kk = 0; kk < 2; ++kk) {
      const bf16x8 pa = __builtin_bit_cast(bf16x8, pw[kk]);
      const int cb = (kk ? vb1 : vb0) + 16384 + buf * 8192;
#pragma unroll
      for (int et = 0; et < 4; ++et) {
        const bf16x8 vf = *(const bf16x8*)(sb + (cb + et * 2048));
        o[et] = __builtin_amdgcn_mfma_f32_16x16x32_bf16(vf, pa, o[et], 0, 0, 0);
      }
    }
    __syncthreads();
  }

  // epilogue: reduce l across the 4 k-group lanes, transpose via padded LDS (per-wave
  // region -> lgkmcnt wait only), coalesced float4 RMW into Out
  float lt = l_run;
  lt += __shfl_xor(lt, 16);
  lt += __shfl_xor(lt, 32);
  const float inv = 1.0f / lt;
  float* Ep = (float*)smem + wid * 1088;   // 16 x 68 fp32 per wave
  const int b = bh >> 4, h = bh & 15;
#pragma unroll
  for (int et = 0; et < 4; ++et) {
    f32x4 v = o[et] * inv;
    *(float4v*)&Ep[lr * 68 + et * 16 + hi * 4] = v;
  }
  asm volatile("s_waitcnt lgkmcnt(0)" ::: "memory");
  const int qr = lane >> 2, cc = lane & 3;
  const size_t gb = ((size_t)b * 2048 + q0 + wid * 16 + qr) * 1024 + h * 64 + cc * 4;
#pragma unroll
  for (int i = 0; i < 4; ++i) {
    float4v v = *(const float4v*)&Ep[qr * 68 + cc * 4 + i * 16];
    float4v u = *(const float4v*)&Out[gb + i * 16];
    u += v;
    *(float4v*)&Out[gb + i * 16] = u;
  }
#undef GLL
}

extern "C" void kernel_launch(void* const* d_in, const int* in_sizes, int n_in,
                              void* d_out, int out_size, void* d_ws, size_t ws_size,
                              hipStream_t stream) {
  const float* x  = (const float*)d_in[0];
  const float* Wq = (const float*)d_in[1];
  const float* bq = (const float*)d_in[2];
  const float* Wk = (const float*)d_in[3];
  const float* bk = (const float*)d_in[4];
  const float* Wv = (const float*)d_in[5];
  const float* bv = (const float*)d_in[6];
  const float* Wr = (const float*)d_in[7];
  const float* br = (const float*)d_in[8];
  float* Out = (float*)d_out;

  char* ws = (char*)d_ws;
  short* Xb = (short*)(ws);                                  // 16 MiB [8192][1024]
  short* Wc = (short*)(ws + (size_t)16 * 1024 * 1024);       //  8 MiB [4096][1024]
  short* Qb = (short*)(ws + (size_t)24 * 1024 * 1024);       // 16 MiB [B][H][S][E]
  short* Kb = (short*)(ws + (size_t)40 * 1024 * 1024);       // 16 MiB
  short* Vb = (short*)(ws + (size_t)56 * 1024 * 1024);       // 16 MiB
  short* Vt = (short*)(ws);                                  // 16 MiB [B][H][E][S'] (reuses Xb)

  k_cvt_x<<<8192, 256, 0, stream>>>(x, Xb);
  k_cvt_w<<<1024, 256, 0, stream>>>(Wq, Wk, Wv, Wr, Wc);
  k_gemm<<<2048, 256, 0, stream>>>(Xb, Wc, bq, bk, bv, br, Qb, Kb, Vb, Out);
  k_tr_v<<<2048, 256, 0, stream>>>(Vb, Vt);
  k_attn<<<2048, 256, 0, stream>>>(Qb, Kb, Vt, Out);
}